// Round 1
// baseline (97.707 us; speedup 1.0000x reference)
//
#include <hip/hip_runtime.h>

typedef short s16x8 __attribute__((ext_vector_type(8)));
typedef float f32x4 __attribute__((ext_vector_type(4)));

#define NB      1024
#define NCLASS  50
#define NCENTER 8
#define HID     512
#define KPAD    64
#define MROWS   8192   // NB*NCENTER

// workspace byte offsets (all 16B aligned)
#define OFF_ABF    0u          // 8192*512*2  = 8388608
#define OFF_WT     8388608u    // 512*512*2   = 524288
#define OFF_MUBF   8912896u    // 8*64*512*2  = 524288
#define OFF_MUNORM 9437184u    // 8*64*4      = 2048
#define OFF_MULBF  9439232u    // 8192*512*2  = 8388608
#define OFF_SCORE  17827840u   // 1024*64*8*4 = 2097152
// total = 19,924,992 bytes

// output layout (element offsets in d_out, fp32)
#define OUT_KA 4194304   // after mul [1024*8*512]
#define OUT_D  4603904   // after k_assign [1024*50*8]

__device__ __forceinline__ short f2bf(float f) {
    unsigned int u = __float_as_uint(f);
    unsigned int r = (u + 0x7FFFu + ((u >> 16) & 1u)) >> 16;  // RNE
    return (short)(unsigned short)r;
}
__device__ __forceinline__ float bf2f(short h) {
    return __uint_as_float(((unsigned int)(unsigned short)h) << 16);
}

// ---------------------------------------------------------------------------
// Kernel 1: prep. blocks [0,256): masked A -> bf16; [256,320): W^T -> bf16
// (LDS transpose); [320,448): class_mu -> padded bf16 + fp32 norms.
// ---------------------------------------------------------------------------
__global__ __launch_bounds__(256) void prep_kernel(
    const float* __restrict__ x, const float* __restrict__ class_mu,
    const float* __restrict__ mask, const float* __restrict__ W,
    short* __restrict__ Abf, short* __restrict__ WT,
    short* __restrict__ Mubf, float* __restrict__ Munorm)
{
    __shared__ float lds[64][65];
    const int blk = blockIdx.x, tid = threadIdx.x;

    if (blk < 256) {
        // A[(b*8+c), k] = bf16(x[b,k] * mask[c,k]); 524288 groups of 8 elems
        #pragma unroll
        for (int i = 0; i < 8; ++i) {
            int g = (blk * 256 + tid) + i * 65536;
            int e = g * 8;
            int r = e >> 9;        // row (b*8+c)
            int k = e & 511;
            int b = r >> 3, c = r & 7;
            const float4* xp = (const float4*)(x + b * HID + k);
            const float4* mp = (const float4*)(mask + c * HID + k);
            float4 x0 = xp[0], x1 = xp[1];
            float4 m0 = mp[0], m1 = mp[1];
            s16x8 o;
            o[0] = f2bf(x0.x * m0.x); o[1] = f2bf(x0.y * m0.y);
            o[2] = f2bf(x0.z * m0.z); o[3] = f2bf(x0.w * m0.w);
            o[4] = f2bf(x1.x * m1.x); o[5] = f2bf(x1.y * m1.y);
            o[6] = f2bf(x1.z * m1.z); o[7] = f2bf(x1.w * m1.w);
            *(s16x8*)(Abf + e) = o;
        }
    } else if (blk < 320) {
        // WT[d][h] = bf16(W[h][d]), 64x64 tile per block
        int t = blk - 256;
        int th = t & 7, td = t >> 3;          // h-tile, d-tile
        int col = tid & 63, rb = tid >> 6;
        #pragma unroll
        for (int it = 0; it < 16; ++it) {
            int row = it * 4 + rb;
            lds[row][col] = W[(th * 64 + row) * HID + td * 64 + col];
        }
        __syncthreads();
        #pragma unroll
        for (int it = 0; it < 16; ++it) {
            int row = it * 4 + rb;
            WT[(td * 64 + row) * HID + th * 64 + col] = f2bf(lds[col][row]);
        }
    } else {
        // one wave per (c, kk): Mubf[c][kk][h] (kk>=50 zero-padded), Munorm
        int w = (blk - 320) * 4 + (tid >> 6);   // 0..511
        int lane = tid & 63;
        int c = w >> 6, kk = w & 63;
        int h = lane * 8;
        float v[8];
        if (kk < NCLASS) {
            const float4* p = (const float4*)(class_mu + (kk * NCENTER + c) * HID + h);
            float4 a = p[0], bq = p[1];
            v[0] = a.x;  v[1] = a.y;  v[2] = a.z;  v[3] = a.w;
            v[4] = bq.x; v[5] = bq.y; v[6] = bq.z; v[7] = bq.w;
        } else {
            #pragma unroll
            for (int j = 0; j < 8; ++j) v[j] = 0.f;
        }
        s16x8 o; float sq = 0.f;
        #pragma unroll
        for (int j = 0; j < 8; ++j) { o[j] = f2bf(v[j]); sq += v[j] * v[j]; }
        *(s16x8*)(Mubf + (c * KPAD + kk) * HID + h) = o;
        sq += __shfl_xor(sq, 1);  sq += __shfl_xor(sq, 2);  sq += __shfl_xor(sq, 4);
        sq += __shfl_xor(sq, 8);  sq += __shfl_xor(sq, 16); sq += __shfl_xor(sq, 32);
        if (lane == 0) Munorm[c * KPAD + kk] = sq;
    }
}

// ---------------------------------------------------------------------------
// Kernel 2: mul = A(bf16, M=8192 x K=512) @ W (via W^T, N=512).
// 128x128 block tile, 4 waves in 2x2, each wave 64x64 via 4x4 of 16x16x32.
// Writes fp32 mul to d_out and bf16 copy to ws for the score GEMM.
// ---------------------------------------------------------------------------
__global__ __launch_bounds__(256) void gemm_mul(
    const short* __restrict__ Abf, const short* __restrict__ WT,
    float* __restrict__ mul_out, short* __restrict__ mulbf)
{
    __shared__ short As[128 * 32];
    __shared__ short Bs[128 * 32];
    const int tid = threadIdx.x;
    const int bm = blockIdx.x * 128;
    const int bn = blockIdx.y * 128;
    const int wave = tid >> 6, lane = tid & 63;
    const int wm = (wave & 1) * 64, wn = (wave >> 1) * 64;
    const int q = lane >> 4, l16 = lane & 15;

    f32x4 acc[4][4] = {};

    const int r0 = tid >> 2, c0 = (tid & 3) * 8;  // staging: rows r0 and r0+64

    for (int it = 0; it < 16; ++it) {
        const int k0 = it * 32;
        *(s16x8*)(As + r0 * 32 + c0)        = *(const s16x8*)(Abf + (bm + r0) * HID + k0 + c0);
        *(s16x8*)(As + (r0 + 64) * 32 + c0) = *(const s16x8*)(Abf + (bm + r0 + 64) * HID + k0 + c0);
        *(s16x8*)(Bs + r0 * 32 + c0)        = *(const s16x8*)(WT + (bn + r0) * HID + k0 + c0);
        *(s16x8*)(Bs + (r0 + 64) * 32 + c0) = *(const s16x8*)(WT + (bn + r0 + 64) * HID + k0 + c0);
        __syncthreads();

        s16x8 af[4], bfr[4];
        #pragma unroll
        for (int mt = 0; mt < 4; ++mt)
            af[mt] = *(const s16x8*)(As + (wm + mt * 16 + l16) * 32 + q * 8);
        #pragma unroll
        for (int nt = 0; nt < 4; ++nt)
            bfr[nt] = *(const s16x8*)(Bs + (wn + nt * 16 + l16) * 32 + q * 8);
        #pragma unroll
        for (int mt = 0; mt < 4; ++mt)
            #pragma unroll
            for (int nt = 0; nt < 4; ++nt)
                acc[mt][nt] = __builtin_amdgcn_mfma_f32_16x16x32_bf16(af[mt], bfr[nt], acc[mt][nt], 0, 0, 0);
        __syncthreads();
    }

    // epilogue: C/D layout col=lane&15, row=(lane>>4)*4+reg
    #pragma unroll
    for (int mt = 0; mt < 4; ++mt) {
        #pragma unroll
        for (int nt = 0; nt < 4; ++nt) {
            #pragma unroll
            for (int reg = 0; reg < 4; ++reg) {
                int gr = bm + wm + mt * 16 + q * 4 + reg;
                int gc = bn + wn + nt * 16 + l16;
                float v = acc[mt][nt][reg];
                mul_out[gr * HID + gc] = v;
                mulbf[gr * HID + gc] = f2bf(v);
            }
        }
    }
}

// ---------------------------------------------------------------------------
// Kernel 3: per (center c, 32-row b tile): score[b][k][c] = 1/(1+||mul-mu||^2)
// via ||mul||^2 - 2*mul.mu + ||mu||^2. 2 waves/block, each 16 b x 64 classes.
// ---------------------------------------------------------------------------
__global__ __launch_bounds__(128) void score_kernel(
    const short* __restrict__ mulbf, const short* __restrict__ Mubf,
    const float* __restrict__ Munorm, float* __restrict__ score)
{
    const int tid = threadIdx.x;
    const int c = blockIdx.x & 7, bt = blockIdx.x >> 3;
    const int wave = tid >> 6, lane = tid & 63;
    const int q = lane >> 4, l16 = lane & 15;
    const int b0 = bt * 32 + wave * 16;

    f32x4 acc[4] = {};
    float nrm = 0.f;

    const short* arow = mulbf + ((b0 + l16) * NCENTER + c) * HID + q * 8;
    const short* brow = Mubf + (c * KPAD + l16) * HID + q * 8;

    for (int it = 0; it < 16; ++it) {
        const int k0 = it * 32;
        s16x8 av  = *(const s16x8*)(arow + k0);
        s16x8 bv0 = *(const s16x8*)(brow + k0);
        s16x8 bv1 = *(const s16x8*)(brow + 16 * HID + k0);
        s16x8 bv2 = *(const s16x8*)(brow + 32 * HID + k0);
        s16x8 bv3 = *(const s16x8*)(brow + 48 * HID + k0);
        #pragma unroll
        for (int j = 0; j < 8; ++j) { float f = bf2f(av[j]); nrm += f * f; }
        acc[0] = __builtin_amdgcn_mfma_f32_16x16x32_bf16(av, bv0, acc[0], 0, 0, 0);
        acc[1] = __builtin_amdgcn_mfma_f32_16x16x32_bf16(av, bv1, acc[1], 0, 0, 0);
        acc[2] = __builtin_amdgcn_mfma_f32_16x16x32_bf16(av, bv2, acc[2], 0, 0, 0);
        acc[3] = __builtin_amdgcn_mfma_f32_16x16x32_bf16(av, bv3, acc[3], 0, 0, 0);
    }

    // row norms: lane (q,l16) covered all k for row m=l16 together with its 3
    // xor-16/32 partners
    nrm += __shfl_xor(nrm, 16);
    nrm += __shfl_xor(nrm, 32);
    float rowNorm[4];
    #pragma unroll
    for (int reg = 0; reg < 4; ++reg) rowNorm[reg] = __shfl(nrm, q * 4 + reg);

    #pragma unroll
    for (int nt = 0; nt < 4; ++nt) {
        float mn = Munorm[c * KPAD + nt * 16 + l16];
        #pragma unroll
        for (int reg = 0; reg < 4; ++reg) {
            float sq = rowNorm[reg] + mn - 2.f * acc[nt][reg];
            float sc = 1.f / (1.f + sq);
            int b = b0 + q * 4 + reg;
            int kcls = nt * 16 + l16;
            score[(b * KPAD + kcls) * NCENTER + c] = sc;
        }
    }
}

// ---------------------------------------------------------------------------
// Kernel 4: normalize over centers -> k_assign, distances
// ---------------------------------------------------------------------------
__global__ __launch_bounds__(256) void norm_kernel(
    const float* __restrict__ score, float* __restrict__ out)
{
    int t = blockIdx.x * 256 + threadIdx.x;
    if (t >= NB * NCLASS) return;
    int b = t / NCLASS, k = t % NCLASS;
    const float4* sp = (const float4*)(score + (b * KPAD + k) * NCENTER);
    float4 s0 = sp[0], s1 = sp[1];
    float S = s0.x + s0.y + s0.z + s0.w + s1.x + s1.y + s1.z + s1.w;
    float invd = 1.f / (S + 1e-8f);   // distances = score/(S+eps)
    float invk = 1.f / S;             // k_assign  = score/S
    float4 ka0, ka1, dd0, dd1;
    ka0.x = s0.x * invk; ka0.y = s0.y * invk; ka0.z = s0.z * invk; ka0.w = s0.w * invk;
    ka1.x = s1.x * invk; ka1.y = s1.y * invk; ka1.z = s1.z * invk; ka1.w = s1.w * invk;
    dd0.x = s0.x * invd; dd0.y = s0.y * invd; dd0.z = s0.z * invd; dd0.w = s0.w * invd;
    dd1.x = s1.x * invd; dd1.y = s1.y * invd; dd1.z = s1.z * invd; dd1.w = s1.w * invd;
    float* kap = out + OUT_KA + (b * NCLASS + k) * NCENTER;
    float* dp  = out + OUT_D  + (b * NCLASS + k) * NCENTER;
    ((float4*)kap)[0] = ka0; ((float4*)kap)[1] = ka1;
    ((float4*)dp)[0]  = dd0; ((float4*)dp)[1]  = dd1;
}

extern "C" void kernel_launch(void* const* d_in, const int* in_sizes, int n_in,
                              void* d_out, int out_size, void* d_ws, size_t ws_size,
                              hipStream_t stream) {
    const float* x        = (const float*)d_in[0];
    const float* class_mu = (const float*)d_in[1];
    const float* mask     = (const float*)d_in[2];
    const float* W        = (const float*)d_in[3];
    float* out = (float*)d_out;
    char* ws = (char*)d_ws;

    short* Abf    = (short*)(ws + OFF_ABF);
    short* WT     = (short*)(ws + OFF_WT);
    short* Mubf   = (short*)(ws + OFF_MUBF);
    float* Munorm = (float*)(ws + OFF_MUNORM);
    short* mulbf  = (short*)(ws + OFF_MULBF);
    float* score  = (float*)(ws + OFF_SCORE);

    prep_kernel<<<448, 256, 0, stream>>>(x, class_mu, mask, W, Abf, WT, Mubf, Munorm);
    gemm_mul<<<dim3(64, 4), 256, 0, stream>>>(Abf, WT, out, mulbf);
    score_kernel<<<256, 128, 0, stream>>>(mulbf, Mubf, Munorm, score);
    norm_kernel<<<200, 256, 0, stream>>>(score, out);
}